// Round 2
// baseline (1652.455 us; speedup 1.0000x reference)
//
#include <hip/hip_runtime.h>

// z = conv3x3(x, w) (pad 1, cross-correlation, NCHW/OIHW); LIF scan over t:
//   v = v + (z - v)*0.5 ; s = (v >= 1) ; v = s ? 0 : v
// NUMERICS INVARIANT (verified bit-exact R5/R6): per output element the conv
// is a SINGLE sequential f32 FMA chain over k = (tap, ci), tap = ky*3+kx
// outer, ci INNERMOST (Eigen/XLA-CPU order), acc starts at 0; padding taps are
// exact fma no-ops (zero halo). LIF ops separately rounded; *0.5 exact (f32
// store/load round-trip of z is exact, so keeping z=acc in registers is
// bit-identical to the split-kernel version).
// R9: FUSED conv+LIF. Block = (n, 8x8 tile), 4 waves x 16 couts (R7 geometry,
// proven 530us), loops t=0..15 carrying v[16] in registers -> lif_kernel and
// the 268 MB z round-trip eliminated. 512 blocks = exactly 2 blocks/CU.
// LDS read swizzle FIXED vs R8: granule slot = pos*17 + (q ^ ((pos/10)&7));
// the 8 lanes sharing pos%8 have distinct py, and pos/10 = py+ky exactly, so
// every 8-lane row hits all 8 bank groups -> ds_read_b128 conflict-free.
// Read side g = (py+ky)&7 is 1 VALU op per tap.

namespace {
constexpr int T = 16, N = 8, C = 64, H = 64, W = 64;
constexpr int HW   = H * W;       // 4096
constexpr int CHW  = C * HW;      // 262144
constexpr int NCHW = N * CHW;     // 2097152
constexpr int NWT  = C * C * 9;   // 36864
constexpr int PSTR = 68;          // LDS pos-stride in floats (17 float4 granules)
}

// Transpose weights (O,I,3,3) -> wt2[tap][ci][cout]: per (tap,ci) couts are
// contiguous -> wave-uniform s_load of 16 floats per wave per (tap,ci).
__global__ void wtr_kernel(const float* __restrict__ w, float* __restrict__ wt2) {
    int i = blockIdx.x * 256 + threadIdx.x;     // i = (cout*64 + ci)*9 + tap
    if (i >= NWT) return;
    int tap  = i % 9;
    int rem  = i / 9;
    int ci   = rem % 64;
    int cout = rem / 64;
    wt2[(tap * 64 + ci) * 64 + cout] = w[i];
}

// Fused conv+LIF. Block: 256 threads = 4 waves = one (n, 8x8 tile), 64 couts.
// Wave w: 64 lanes = 64 pixels; couts [16w, 16w+16). Loops t, v in registers.
// LDS element (pos, ci) at float slot pos*68 + 4*((ci>>2) ^ ((pos/10)&7)) + (ci&3).
__global__ __launch_bounds__(256, 2) void fused_kernel(
    const float* __restrict__ x,
    const float* __restrict__ wt2,
    float*       __restrict__ out)
{
#pragma clang fp contract(off)
    __shared__ float xs[100 * PSTR];   // pos = dy*10+dx in [0,100), 27.2 KB

    const int tid  = threadIdx.x;
    const int wave = __builtin_amdgcn_readfirstlane(tid >> 6);
    const int lane = tid & 63;
    const int px = lane & 7;
    const int py = lane >> 3;
    const int c0 = wave << 4;          // 16 couts per wave

    const int bid  = blockIdx.x;       // 512 = 8 n * 64 tiles
    const int n    = bid >> 6;
    const int tile = bid & 63;
    const int th0 = (tile >> 3) << 3;
    const int tw0 = (tile & 7) << 3;

    const float* xn = x   + (size_t)n * CHW;
    float*       on = out + (size_t)n * CHW;

    const int pbase = (th0 + py) * W + (tw0 + px);

    float v[16];
#pragma unroll
    for (int i = 0; i < 16; ++i) v[i] = 0.0f;

#pragma unroll 1
    for (int t = 0; t < T; ++t) {
        const float* xt = xn + (size_t)t * NCHW;

        __syncthreads();               // previous compute done reading LDS
        // Stage x[t][n][ci][th0-1..+8][tw0-1..+8] into swizzled LDS (zero halo).
#pragma unroll
        for (int it = 0; it < 25; ++it) {              // 6400 = 25 * 256
            int j  = tid + it * 256;
            int ci = j / 100;
            int rr = j - ci * 100;
            int dy = rr / 10;
            int dx = rr - dy * 10;
            int hh = th0 - 1 + dy;
            int ww = tw0 - 1 + dx;
            float val = 0.0f;
            if ((unsigned)hh < (unsigned)H && (unsigned)ww < (unsigned)W)
                val = xt[ci * HW + hh * W + ww];
            xs[rr * PSTR + ((((ci >> 2) ^ (dy & 7)) << 2) | (ci & 3))] = val;
        }
        __syncthreads();

        float acc[16];
#pragma unroll
        for (int i = 0; i < 16; ++i) acc[i] = 0.0f;

        // Chain per acc[cc]: tap outer (9), ci 0..63 ascending inner; one fmaf
        // per k; only load scheduling varies, never FMA order.
        for (int tap = 0; tap < 9; ++tap) {
            const int ky = tap / 3, kx = tap - 3 * ky;
            const int pos = (py + ky) * 10 + (px + kx);
            const int g   = (py + ky) & 7;              // = (pos/10)&7 exactly
            const float4* xp = (const float4*)xs + pos * (PSTR / 4);
            const float* wtap = wt2 + tap * 4096 + c0;  // wave-uniform
#pragma unroll 4
            for (int cib = 0; cib < 16; ++cib) {
                const float4 xv = xp[cib ^ g];
                const float* wp = wtap + cib * 256;     // (tap, ci=4*cib) block
#pragma unroll
                for (int cc = 0; cc < 16; ++cc)
                    acc[cc] = fmaf(wp[cc], xv.x, acc[cc]);
#pragma unroll
                for (int cc = 0; cc < 16; ++cc)
                    acc[cc] = fmaf(wp[64 + cc], xv.y, acc[cc]);
#pragma unroll
                for (int cc = 0; cc < 16; ++cc)
                    acc[cc] = fmaf(wp[128 + cc], xv.z, acc[cc]);
#pragma unroll
                for (int cc = 0; cc < 16; ++cc)
                    acc[cc] = fmaf(wp[192 + cc], xv.w, acc[cc]);
            }
        }

        // LIF update + spike store (ops identical to the old lif_kernel).
        float* ot = on + (size_t)t * NCHW;
#pragma unroll
        for (int cc = 0; cc < 16; ++cc) {
            float z = acc[cc];
            float d = z - v[cc];
            float h = d * 0.5f;
            float vv = v[cc] + h;
            float s;
            if (vv >= 1.0f) { s = 1.0f; vv = 0.0f; } else { s = 0.0f; }
            v[cc] = vv;
            ot[(c0 + cc) * HW + pbase] = s;
        }
    }
}

extern "C" void kernel_launch(void* const* d_in, const int* in_sizes, int n_in,
                              void* d_out, int out_size, void* d_ws, size_t ws_size,
                              hipStream_t stream) {
    const float* x = (const float*)d_in[0];
    const float* w = (const float*)d_in[1];
    if (n_in >= 2 && in_sizes[0] < in_sizes[1]) {   // defensive: pick by size
        const float* tmp = x; x = w; w = tmp;
    }
    float* out = (float*)d_out;
    float* wt2 = (float*)d_ws;                       // 36864 floats = 144 KB

    wtr_kernel<<<(NWT + 255) / 256, 256, 0, stream>>>(w, wt2);
    fused_kernel<<<N * 64, 256, 0, stream>>>(x, wt2, out);
}

// Round 3
// 665.117 us; speedup vs baseline: 2.4845x; 2.4845x over previous
//
#include <hip/hip_runtime.h>

// z = conv3x3(x, w) (pad 1, cross-correlation, NCHW/OIHW); LIF scan over t:
//   v = v + (z - v)*0.5 ; s = (v >= 1) ; v = s ? 0 : v
// NUMERICS INVARIANT (verified bit-exact R5/R6): per output element the conv
// is a SINGLE sequential f32 FMA chain over k = (tap, ci), tap = ky*3+kx
// outer, ci INNERMOST (Eigen/XLA-CPU order), acc starts at 0; padding taps are
// exact fma no-ops (zero halo). LIF ops separately rounded; *0.5 exact.
// R10: revert to R7 split structure (proven 530us conv). ONE change in conv:
// LDS layout transposed to [ci_granule][pos] (granule slot = cib*100 + pos).
// Eliminates the PSTR=68 pad -> LDS 27.2KB -> 25.6KB -> 6 blocks/CU (was 5),
// 24 waves/CU. Bank structure provably identical to R7 for reads ((4pos+c)
// mod 32) and staging writes ((4rr+c) mod 32); cib read offsets fold into
// ds_read immediates (cib*1600B). FMA chain bit-identical. LIF: float4.

namespace {
constexpr int T = 16, N = 8, C = 64, H = 64, W = 64;
constexpr int HW   = H * W;       // 4096
constexpr int CHW  = C * HW;      // 262144
constexpr int NCHW = N * CHW;     // 2097152
constexpr int NWT  = C * C * 9;   // 36864
}

// Transpose weights (O,I,3,3) -> wt2[tap][ci][cout]: per (tap,ci) couts are
// contiguous -> wave-uniform s_load of 16 floats per wave per (tap,ci).
__global__ void wtr_kernel(const float* __restrict__ w, float* __restrict__ wt2) {
    int i = blockIdx.x * 256 + threadIdx.x;     // i = (cout*64 + ci)*9 + tap
    if (i >= NWT) return;
    int tap  = i % 9;
    int rem  = i / 9;
    int ci   = rem % 64;
    int cout = rem / 64;
    wt2[(tap * 64 + ci) * 64 + cout] = w[i];
}

// Conv only. Block: 256 threads = 4 waves = one (t, n, 8x8 tile), 64 couts.
// Wave w: 64 lanes = 64 pixels; couts [16w, 16w+16). Writes z into `zo`.
// LDS float4-granule layout: granule slot = cib*100 + pos, pos = dy*10+dx.
// Element (pos, ci) at float slot (ci>>2)*400 + pos*4 + (ci&3).
__global__ __launch_bounds__(256, 6) void conv_kernel(
    const float* __restrict__ x,
    const float* __restrict__ wt2,
    float*       __restrict__ zo)
{
#pragma clang fp contract(off)
    __shared__ float xs[16 * 400];     // 16 ci-granules x 100 pos x float4 = 25.6KB

    const int tid  = threadIdx.x;
    const int wave = __builtin_amdgcn_readfirstlane(tid >> 6);
    const int lane = tid & 63;
    const int px = lane & 7;
    const int py = lane >> 3;
    const int c0 = wave << 4;          // 16 couts per wave

    const int bid  = blockIdx.x;       // 8192 = 16 t * 8 n * 64 tiles
    const int t    = bid >> 9;
    const int r    = bid & 511;
    const int n    = r >> 6;
    const int tile = r & 63;
    const int th0 = (tile >> 3) << 3;
    const int tw0 = (tile & 7) << 3;

    const float* xt = x + (size_t)(t * N + n) * CHW;

    // Stage x[t][n][ci][th0-1..+8][tw0-1..+8] transposed into LDS (zero halo).
#pragma unroll
    for (int it = 0; it < 25; ++it) {              // 6400 = 25 * 256
        int j  = tid + it * 256;
        int ci = j / 100;
        int rr = j - ci * 100;
        int dy = rr / 10;
        int dx = rr - dy * 10;
        int hh = th0 - 1 + dy;
        int ww = tw0 - 1 + dx;
        float val = 0.0f;
        if ((unsigned)hh < (unsigned)H && (unsigned)ww < (unsigned)W)
            val = xt[ci * HW + hh * W + ww];
        xs[(ci >> 2) * 400 + rr * 4 + (ci & 3)] = val;
    }
    __syncthreads();

    float acc[16];
#pragma unroll
    for (int i = 0; i < 16; ++i) acc[i] = 0.0f;

    // Chain per acc[cc]: tap outer (9), ci 0..63 ascending inner; one fmaf
    // per k; only load scheduling varies, never FMA order.
    for (int tap = 0; tap < 9; ++tap) {
        const int ky = tap / 3, kx = tap - 3 * ky;
        const int pos = (py + ky) * 10 + (px + kx);
        const float4* xp = (const float4*)xs + pos;      // + cib*100 granules
        const float* wtap = wt2 + tap * 4096 + c0;       // wave-uniform
#pragma unroll 2
        for (int cib = 0; cib < 16; ++cib) {
            const float4 xv = xp[cib * 100];             // offset imm = cib*1600B
            const float* wp = wtap + cib * 256;          // (tap, ci=4*cib) block
#pragma unroll
            for (int cc = 0; cc < 16; ++cc)
                acc[cc] = fmaf(wp[cc], xv.x, acc[cc]);
#pragma unroll
            for (int cc = 0; cc < 16; ++cc)
                acc[cc] = fmaf(wp[64 + cc], xv.y, acc[cc]);
#pragma unroll
            for (int cc = 0; cc < 16; ++cc)
                acc[cc] = fmaf(wp[128 + cc], xv.z, acc[cc]);
#pragma unroll
            for (int cc = 0; cc < 16; ++cc)
                acc[cc] = fmaf(wp[192 + cc], xv.w, acc[cc]);
        }
    }

    float* zt = zo + (size_t)(t * N + n) * CHW;
    const int pbase = (th0 + py) * W + (tw0 + px);
#pragma unroll
    for (int cc = 0; cc < 16; ++cc)
        zt[(c0 + cc) * HW + pbase] = acc[cc];
}

// LIF scan, in-place on zo (reads z, writes 0/1 spikes). One thread per FOUR
// consecutive (n,c,h,w) neurons (float4); t-loop carries v in registers.
// Elementwise ops separately rounded, identical per-element order.
__global__ void lif_kernel(float* __restrict__ zo) {
#pragma clang fp contract(off)
    const int gid = blockIdx.x * 256 + threadIdx.x;   // [0, NCHW/4)
    float4 v;
    v.x = 0.0f; v.y = 0.0f; v.z = 0.0f; v.w = 0.0f;
#pragma unroll
    for (int t = 0; t < T; ++t) {
        float4* p = (float4*)(zo + (size_t)t * NCHW) + gid;
        float4 z = *p;
        float4 s;
#define LIF_STEP(comp) { float d = z.comp - v.comp; float hh = d * 0.5f;      \
        v.comp = v.comp + hh;                                                  \
        if (v.comp >= 1.0f) { s.comp = 1.0f; v.comp = 0.0f; }                  \
        else                { s.comp = 0.0f; } }
        LIF_STEP(x) LIF_STEP(y) LIF_STEP(z) LIF_STEP(w)
#undef LIF_STEP
        *p = s;
    }
}

extern "C" void kernel_launch(void* const* d_in, const int* in_sizes, int n_in,
                              void* d_out, int out_size, void* d_ws, size_t ws_size,
                              hipStream_t stream) {
    const float* x = (const float*)d_in[0];
    const float* w = (const float*)d_in[1];
    if (n_in >= 2 && in_sizes[0] < in_sizes[1]) {   // defensive: pick by size
        const float* tmp = x; x = w; w = tmp;
    }
    float* out = (float*)d_out;
    float* wt2 = (float*)d_ws;                       // 36864 floats = 144 KB

    wtr_kernel<<<(NWT + 255) / 256, 256, 0, stream>>>(w, wt2);
    conv_kernel<<<T * N * 64, 256, 0, stream>>>(x, wt2, out);
    lif_kernel<<<NCHW / 1024, 256, 0, stream>>>(out);
}

// Round 4
// 636.703 us; speedup vs baseline: 2.5953x; 1.0446x over previous
//
#include <hip/hip_runtime.h>

// z = conv3x3(x, w) (pad 1, cross-correlation, NCHW/OIHW); LIF scan over t:
//   v = v + (z - v)*0.5 ; s = (v >= 1) ; v = s ? 0 : v
// NUMERICS INVARIANT (verified bit-exact R5/R6): per output element the conv
// is a SINGLE sequential f32 FMA chain over k = (tap, ci), tap = ky*3+kx
// outer, ci INNERMOST (Eigen/XLA-CPU order), acc starts at 0; padding taps are
// exact fma no-ops (zero halo). LIF ops separately rounded; *0.5 exact.
// R11: amortize the weight s_load stall. Tile 16w x 8h, TWO pixels per lane
// (px and px+8), acc[2][16]: the same 4 s_load_dwordx16 per cib now feed 128
// FMAs (was 64) -> weight-latency per FMA halved. ds_read:FMA unchanged; FMA
// chain per output bit-identical. LDS 46KB -> 3 blocks/CU (R10 showed
// occupancy is not the lever). LIF: 2 independent float4 chains per thread.

namespace {
constexpr int T = 16, N = 8, C = 64, H = 64, W = 64;
constexpr int HW   = H * W;       // 4096
constexpr int CHW  = C * HW;      // 262144
constexpr int NCHW = N * CHW;     // 2097152
constexpr int NWT  = C * C * 9;   // 36864
constexpr int NPOS = 10 * 18;     // 180 halo positions (8+2 rows, 16+2 cols)
}

// Transpose weights (O,I,3,3) -> wt2[tap][ci][cout]: per (tap,ci) couts are
// contiguous -> wave-uniform s_load of 16 floats per wave per (tap,ci).
__global__ void wtr_kernel(const float* __restrict__ w, float* __restrict__ wt2) {
    int i = blockIdx.x * 256 + threadIdx.x;     // i = (cout*64 + ci)*9 + tap
    if (i >= NWT) return;
    int tap  = i % 9;
    int rem  = i / 9;
    int ci   = rem % 64;
    int cout = rem / 64;
    wt2[(tap * 64 + ci) * 64 + cout] = w[i];
}

// Conv only. Block: 256 threads = 4 waves = one (t, n, 8x16 tile), 64 couts.
// Wave w: 64 lanes cover all 128 pixels (2 per lane: px, px+8); couts
// [16w, 16w+16). LDS float4-granule layout: granule = cib*NPOS + pos,
// pos = dy*18+dx; element (pos,ci) at float slot (ci>>2)*720 + pos*4 + (ci&3).
__global__ __launch_bounds__(256, 3) void conv_kernel(
    const float* __restrict__ x,
    const float* __restrict__ wt2,
    float*       __restrict__ zo)
{
#pragma clang fp contract(off)
    __shared__ float xs[16 * NPOS * 4];   // 16 ci-granules x 180 pos x 16B = 46.08KB

    const int tid  = threadIdx.x;
    const int wave = __builtin_amdgcn_readfirstlane(tid >> 6);
    const int lane = tid & 63;
    const int px = lane & 7;           // second pixel at px+8
    const int py = lane >> 3;
    const int c0 = wave << 4;          // 16 couts per wave

    const int bid  = blockIdx.x;       // 4096 = 16 t * 8 n * 32 tiles
    const int t    = bid >> 8;
    const int r    = bid & 255;
    const int n    = r >> 5;
    const int tile = r & 31;
    const int th0 = (tile >> 2) << 3;  // 8 row-tiles
    const int tw0 = (tile & 3) << 4;   // 4 col-tiles (16 wide)

    const float* xt = x + (size_t)(t * N + n) * CHW;

    // Stage x[t][n][ci][th0-1..+8][tw0-1..+16] transposed into LDS (zero halo).
#pragma unroll
    for (int it = 0; it < 45; ++it) {              // 11520 = 45 * 256
        int j  = tid + it * 256;
        int ci = j / NPOS;
        int rr = j - ci * NPOS;
        int dy = rr / 18;
        int dx = rr - dy * 18;
        int hh = th0 - 1 + dy;
        int ww = tw0 - 1 + dx;
        float val = 0.0f;
        if ((unsigned)hh < (unsigned)H && (unsigned)ww < (unsigned)W)
            val = xt[ci * HW + hh * W + ww];
        xs[(ci >> 2) * (NPOS * 4) + rr * 4 + (ci & 3)] = val;
    }
    __syncthreads();

    float acc0[16], acc1[16];
#pragma unroll
    for (int i = 0; i < 16; ++i) { acc0[i] = 0.0f; acc1[i] = 0.0f; }

    // Chain per acc[cc]: tap outer (9), ci 0..63 ascending inner; one fmaf
    // per k; only load scheduling varies, never FMA order. Both pixels'
    // chains are independent and identically ordered.
    for (int tap = 0; tap < 9; ++tap) {
        const int ky = tap / 3, kx = tap - 3 * ky;
        const int pos = (py + ky) * 18 + (px + kx);   // second pixel: pos + 8
        const float4* xp = (const float4*)xs + pos;   // + cib*NPOS granules
        const float* wtap = wt2 + tap * 4096 + c0;    // wave-uniform
#pragma unroll 2
        for (int cib = 0; cib < 16; ++cib) {
            const float4 xv0 = xp[cib * NPOS];
            const float4 xv1 = xp[cib * NPOS + 8];
            const float* wp = wtap + cib * 256;       // (tap, ci=4*cib) block
#pragma unroll
            for (int cc = 0; cc < 16; ++cc) {
                float w0 = wp[cc];
                acc0[cc] = fmaf(w0, xv0.x, acc0[cc]);
                acc1[cc] = fmaf(w0, xv1.x, acc1[cc]);
            }
#pragma unroll
            for (int cc = 0; cc < 16; ++cc) {
                float w1 = wp[64 + cc];
                acc0[cc] = fmaf(w1, xv0.y, acc0[cc]);
                acc1[cc] = fmaf(w1, xv1.y, acc1[cc]);
            }
#pragma unroll
            for (int cc = 0; cc < 16; ++cc) {
                float w2 = wp[128 + cc];
                acc0[cc] = fmaf(w2, xv0.z, acc0[cc]);
                acc1[cc] = fmaf(w2, xv1.z, acc1[cc]);
            }
#pragma unroll
            for (int cc = 0; cc < 16; ++cc) {
                float w3 = wp[192 + cc];
                acc0[cc] = fmaf(w3, xv0.w, acc0[cc]);
                acc1[cc] = fmaf(w3, xv1.w, acc1[cc]);
            }
        }
    }

    float* zt = zo + (size_t)(t * N + n) * CHW;
    const int pbase = (th0 + py) * W + (tw0 + px);
#pragma unroll
    for (int cc = 0; cc < 16; ++cc) {
        zt[(c0 + cc) * HW + pbase]     = acc0[cc];
        zt[(c0 + cc) * HW + pbase + 8] = acc1[cc];
    }
}

// LIF scan, in-place on zo (reads z, writes 0/1 spikes). Each thread owns TWO
// independent float4 neuron groups (gid and gid + TOTAL4/2) -> 2 loads in
// flight on the dependent t-scan. Elementwise op order per element unchanged.
__global__ void lif_kernel(float* __restrict__ zo) {
#pragma clang fp contract(off)
    constexpr int TOTAL4 = NCHW / 4;                  // 524288 float4 per slice
    const int gid = blockIdx.x * 256 + threadIdx.x;   // [0, TOTAL4/2)
    const int gid2 = gid + TOTAL4 / 2;
    float4 va, vb;
    va.x = va.y = va.z = va.w = 0.0f;
    vb.x = vb.y = vb.z = vb.w = 0.0f;
#pragma unroll
    for (int t = 0; t < T; ++t) {
        float4* base = (float4*)(zo + (size_t)t * NCHW);
        float4* pa = base + gid;
        float4* pb = base + gid2;
        float4 za = *pa;
        float4 zb = *pb;
        float4 sa, sb;
#define LIF_STEP(v, z, s, comp) { float d = z.comp - v.comp;                   \
        float hh = d * 0.5f; v.comp = v.comp + hh;                             \
        if (v.comp >= 1.0f) { s.comp = 1.0f; v.comp = 0.0f; }                  \
        else                { s.comp = 0.0f; } }
        LIF_STEP(va, za, sa, x) LIF_STEP(va, za, sa, y)
        LIF_STEP(va, za, sa, z) LIF_STEP(va, za, sa, w)
        LIF_STEP(vb, zb, sb, x) LIF_STEP(vb, zb, sb, y)
        LIF_STEP(vb, zb, sb, z) LIF_STEP(vb, zb, sb, w)
#undef LIF_STEP
        *pa = sa;
        *pb = sb;
    }
}

extern "C" void kernel_launch(void* const* d_in, const int* in_sizes, int n_in,
                              void* d_out, int out_size, void* d_ws, size_t ws_size,
                              hipStream_t stream) {
    const float* x = (const float*)d_in[0];
    const float* w = (const float*)d_in[1];
    if (n_in >= 2 && in_sizes[0] < in_sizes[1]) {   // defensive: pick by size
        const float* tmp = x; x = w; w = tmp;
    }
    float* out = (float*)d_out;
    float* wt2 = (float*)d_ws;                       // 36864 floats = 144 KB

    wtr_kernel<<<(NWT + 255) / 256, 256, 0, stream>>>(w, wt2);
    conv_kernel<<<T * N * 32, 256, 0, stream>>>(x, wt2, out);
    lif_kernel<<<NCHW / 2048, 256, 0, stream>>>(out);
}